// Round 7
// baseline (286.501 us; speedup 1.0000x reference)
//
#include <hip/hip_runtime.h>
#include <hip/hip_fp16.h>
#include <math.h>

#define NB 4
#define GH 64
#define GW 64
#define DM 128
#define MW 256
#define NF 10
#define NPTS 65536
#define ENCD 42
#define MT 128         // points per block: two 64-pt half-tiles A (rows 0-63) and B (64-127)
#define TPB 512
#define LDK 264        // act row stride in f16

typedef _Float16 f16x8 __attribute__((ext_vector_type(8)));
typedef __fp16 h16x2 __attribute__((ext_vector_type(2)));
typedef float f32x4 __attribute__((ext_vector_type(4)));

// d_ws: [0,8192) film fp32 (4x512); [8192,...) packed f16 weights.
// 16x16x32 B-frags: unit = (ktg*16 + nt)*64 + lane, 8 halves each.
#define KTU 8192
#define KT0 0
#define KT1 6
#define KT2 14
#define KT3 22
#define KT_TOTAL 30
#define NUNIT_MAIN (KT_TOTAL * 16 * 64)
#define NUNIT_OUT (8 * 64)
#define OUT_OFF ((size_t)NUNIT_MAIN * 8)

__device__ __forceinline__ float tanh_fast(float v) {
  const float e = __builtin_amdgcn_exp2f(2.8853900818f * v);
  return 1.0f - 2.0f * __builtin_amdgcn_rcpf(1.0f + e);
}

// Fused prep: blocks [0,122) pack weights; blocks [122,126) compute film.
__global__ void prep_kernel(const float* __restrict__ w0, const float* __restrict__ w1,
                            const float* __restrict__ w2, const float* __restrict__ w3,
                            const float* __restrict__ wo,
                            const float* __restrict__ ctx, const float* __restrict__ wf,
                            const float* __restrict__ bf,
                            _Float16* __restrict__ wp, float* __restrict__ filmout) {
  if (blockIdx.x >= 122) {
    const int b = blockIdx.x - 122;
#pragma unroll
    for (int h = 0; h < 2; ++h) {
      const int j = threadIdx.x + h * 256;
      float acc = bf[j];
      for (int k = 0; k < DM; ++k)
        acc = fmaf(ctx[b * DM + k], wf[k * 512 + j], acc);
      filmout[b * 512 + j] = acc;
    }
    return;
  }
  const int u = blockIdx.x * 256 + threadIdx.x;
  const int lane = u & 63;
  if (u < NUNIT_MAIN) {
    const int v = u >> 6;
    const int nt = v & 15;
    const int ktg = v >> 4;
    const float* w; int ktl, K;
    if (ktg < KT1)      { w = w0; ktl = ktg - KT0; K = 170; }
    else if (ktg < KT2) { w = w1; ktl = ktg - KT1; K = 256; }
    else if (ktg < KT3) { w = w2; ktl = ktg - KT2; K = 256; }
    else                { w = w3; ktl = ktg - KT3; K = 256; }
    const int n = nt * 16 + (lane & 15);
    const int kbase = ktl * 32 + (lane >> 4) * 8;
    _Float16* dst = wp + (size_t)u * 8;
#pragma unroll
    for (int j = 0; j < 8; ++j) {
      const int k = kbase + j;
      dst[j] = (_Float16)((k < K) ? w[k * MW + n] : 0.0f);
    }
  } else {
    const int kt = (u - NUNIT_MAIN) >> 6;
    const int col = lane & 15;
    const int kbase = kt * 32 + (lane >> 4) * 8;
    _Float16* dst = wp + (size_t)u * 8;
#pragma unroll
    for (int j = 0; j < 8; ++j)
      dst[j] = (_Float16)((col < 3) ? wo[(kbase + j) * 3 + col] : 0.0f);
  }
}

__global__ __launch_bounds__(TPB, 4) void decoder_kernel(
    const float* __restrict__ grid, const float* __restrict__ coords,
    const float* __restrict__ b0, const float* __restrict__ b1,
    const float* __restrict__ b2, const float* __restrict__ b3,
    const float* __restrict__ bo,
    const float* __restrict__ film, const _Float16* __restrict__ wpack,
    float* __restrict__ out) {
  __shared__ _Float16 act[MT * LDK];   // 67584 B; rows 0-63 = tile A, 64-127 = tile B
  __shared__ float4 cco4[MT];          // 2048 B

  const int tid = threadIdx.x;
  const int lane = tid & 63;
  const int wc = tid >> 6;             // wave 0..7: owns cols wc*32..wc*32+31 (disjoint)
  const int b = blockIdx.x >> 9;
  const int n0 = (blockIdx.x & 511) * MT;

  // packed-GELU constants (hoisted)
  const __half2 gk1 = __float2half2_rn(-2.3022082f);
  const __half2 gk2 = __float2half2_rn(-0.10294324f);
  const __half2 one2 = __float2half2_rn(1.0f);

  // ---- per-point bilinear setup ----
  if (tid < MT) {
    const float x = coords[(size_t)(n0 + tid) * 2 + 0];
    const float y = coords[(size_t)(n0 + tid) * 2 + 1];
    const float cr = (x + 1.0f) * 0.5f * 63.0f;
    const float cc = (y + 1.0f) * 0.5f * 63.0f;
    const float r0f = floorf(cr), q0f = floorf(cc);
    const int r0 = min(max((int)r0f, 0), GH - 1);
    const int q0 = min(max((int)q0f, 0), GW - 1);
    float4 v;
    v.x = __int_as_float(r0);
    v.y = __int_as_float(q0);
    v.z = cr - r0f;
    v.w = cc - q0f;
    cco4[tid] = v;
  }

  // ---- positional encoding (hw sin/cos, revolutions) + zero-pad 170..191 ----
  {
    const int p = tid & (MT - 1);
    const int j = tid >> 7;
    const float x = coords[(size_t)(n0 + p) * 2 + 0];
    const float y = coords[(size_t)(n0 + p) * 2 + 1];
    _Float16* row = act + p * LDK;
    if (j == 0) { row[0] = (_Float16)x; row[1] = (_Float16)y; }
    if (j == 1) {
      for (int c = ENCD + DM; c < ENCD + DM + 22; ++c) row[c] = (_Float16)0.0f;
    }
    for (int i = j; i < NF; i += 4) {
      const float sc = 0.5f * (float)(1 << i);
      const float rx = x * sc, ry = y * sc;
      const float fx = rx - floorf(rx);
      const float fy = ry - floorf(ry);
      row[2 + 4 * i + 0] = (_Float16)__builtin_amdgcn_sinf(fx);
      row[2 + 4 * i + 1] = (_Float16)__builtin_amdgcn_sinf(fy);
      row[2 + 4 * i + 2] = (_Float16)__builtin_amdgcn_cosf(fx);
      row[2 + 4 * i + 3] = (_Float16)__builtin_amdgcn_cosf(fy);
    }
  }
  __syncthreads();

  // ---- bilinear sampling, 4 channels/iter ----
  {
    const float* gb = grid + (size_t)b * (GH * GW * DM);
#pragma unroll
    for (int it = 0; it < (MT * DM / 4) / TPB; ++it) {
      const int idx = it * TPB + tid;
      const int p = idx >> 5;
      const int c = (idx & 31) * 4;
      const float4 cc4 = cco4[p];
      const int r0 = __float_as_int(cc4.x);
      const int q0 = __float_as_int(cc4.y);
      const float frr = cc4.z, frc = cc4.w;
      const int r1 = min(r0 + 1, GH - 1), q1 = min(q0 + 1, GW - 1);
      const float4 v00 = *(const float4*)(gb + (size_t)(r0 * GW + q0) * DM + c);
      const float4 v01 = *(const float4*)(gb + (size_t)(r0 * GW + q1) * DM + c);
      const float4 v10 = *(const float4*)(gb + (size_t)(r1 * GW + q0) * DM + c);
      const float4 v11 = *(const float4*)(gb + (size_t)(r1 * GW + q1) * DM + c);
      float4 vt, vb, vv;
      vt.x = fmaf(v01.x - v00.x, frc, v00.x);
      vt.y = fmaf(v01.y - v00.y, frc, v00.y);
      vt.z = fmaf(v01.z - v00.z, frc, v00.z);
      vt.w = fmaf(v01.w - v00.w, frc, v00.w);
      vb.x = fmaf(v11.x - v10.x, frc, v10.x);
      vb.y = fmaf(v11.y - v10.y, frc, v10.y);
      vb.z = fmaf(v11.z - v10.z, frc, v10.z);
      vb.w = fmaf(v11.w - v10.w, frc, v10.w);
      vv.x = fmaf(vb.x - vt.x, frr, vt.x);
      vv.y = fmaf(vb.y - vt.y, frr, vt.y);
      vv.z = fmaf(vb.z - vt.z, frr, vt.z);
      vv.w = fmaf(vb.w - vt.w, frr, vt.w);
      const h16x2 lo = __builtin_amdgcn_cvt_pkrtz(vv.x, vv.y);
      const h16x2 hi = __builtin_amdgcn_cvt_pkrtz(vv.z, vv.w);
      *(h16x2*)(act + p * LDK + ENCD + c) = lo;
      *(h16x2*)(act + p * LDK + ENCD + c + 2) = hi;
    }
  }

  // ---- FiLM params: this wave owns 2 n-tiles (cols wc*32 + nt*16 + 0..15) ----
  const int colbase = wc * 32 + (lane & 15);
  float g1[2], btv[2];
#pragma unroll
  for (int nt = 0; nt < 2; ++nt) {
    g1[nt] = film[b * 512 + colbase + nt * 16] + 1.0f;
    btv[nt] = film[b * 512 + MW + colbase + nt * 16];
  }
  __syncthreads();

  const int arow = lane & 15;
  const int kq = (lane >> 4) * 8;

  // ---- GEMM-phase state (single accumulator: phases alternate tiles) ----
  // One acc (32 regs) instead of R2's two (64): epi(prev tile) reads acc at
  // phase start, then zero+GEMM(cur tile) refills it. The 32 freed regs fund
  // af[2][4] double-buffering and a persistent cross-phase bb prefetch
  // without crossing the 128-reg cliff (R1/R5/R6 all spilled there).
  f32x4 acc[4][2];
  f16x8 af[2][4];
  f16x8 bb[2][2];
  float cbv[2];

  auto loadB = [&](const _Float16* __restrict__ wl, int kt, f16x8 (&bfr)[2]) {
#pragma unroll
    for (int nt = 0; nt < 2; ++nt)
      bfr[nt] = *(const f16x8*)(wl + ((size_t)((kt * 16 + wc * 2 + nt) * 64 + lane)) * 8);
  };
  auto loadA = [&](int T, int kt, f16x8 (&afr)[4]) {
    const int kof = kt * 32 + kq;
#pragma unroll
    for (int mt = 0; mt < 4; ++mt)
      afr[mt] = *(const f16x8*)(act + (T * 64 + mt * 16 + arow) * LDK + kof);
  };
  auto domfma = [&](f16x8 (&afr)[4], f16x8 (&bfr)[2]) {
#pragma unroll
    for (int mt = 0; mt < 4; ++mt)
#pragma unroll
      for (int nt = 0; nt < 2; ++nt)
        acc[mt][nt] = __builtin_amdgcn_mfma_f32_16x16x32_f16(afr[mt], bfr[nt], acc[mt][nt], 0, 0, 0);
  };

  // packed-f16 GELU on a pair: g = h * rcp(1 + exp2(h * (gk1 + gk2*h^2)))
  auto gelu_pk = [&](h16x2 pk) -> h16x2 {
    __half2 hv = __builtin_bit_cast(__half2, pk);
    __half2 t = __hmul2(hv, hv);
    __half2 w = __hfma2(gk2, t, gk1);
    __half2 z = __hmul2(hv, w);
    __half2 e = h2exp2(z);
    __half2 s = __hadd2(e, one2);
    __half2 r = h2rcp(s);
    __half2 g = __hmul2(hv, r);
    return __builtin_bit_cast(h16x2, g);
  };

  // one epilogue group (of 8) for tile T: g -> (mt = g>>1, nt = g&1)
  auto epi_group = [&](int gI, int T) {
    const int mt = gI >> 1, nt = gI & 1;
    const int col = wc * 32 + nt * 16 + (lane & 15);
    const int rowb = T * 64 + mt * 16 + (lane >> 4) * 4;
    const float v0 = fmaf(acc[mt][nt][0], g1[nt], cbv[nt]);
    const float v1 = fmaf(acc[mt][nt][1], g1[nt], cbv[nt]);
    const float v2 = fmaf(acc[mt][nt][2], g1[nt], cbv[nt]);
    const float v3 = fmaf(acc[mt][nt][3], g1[nt], cbv[nt]);
    const h16x2 gA = gelu_pk(__builtin_amdgcn_cvt_pkrtz(v0, v1));
    const h16x2 gB = gelu_pk(__builtin_amdgcn_cvt_pkrtz(v2, v3));
    act[(rowb + 0) * LDK + col] = (_Float16)gA.x;
    act[(rowb + 1) * LDK + col] = (_Float16)gA.y;
    act[(rowb + 2) * LDK + col] = (_Float16)gB.x;
    act[(rowb + 3) * LDK + col] = (_Float16)gB.y;
  };
  auto epi_all = [&](int T) {
#pragma unroll
    for (int g = 0; g < 8; ++g) epi_group(g, T);
  };

  auto zero = [&]() {
#pragma unroll
    for (int mt = 0; mt < 4; ++mt)
#pragma unroll
      for (int nt = 0; nt < 2; ++nt)
        acc[mt][nt] = (f32x4){0.f, 0.f, 0.f, 0.f};
  };

  auto set_cb = [&](const float* __restrict__ bl) {
#pragma unroll
    for (int nt = 0; nt < 2; ++nt)
      cbv[nt] = fmaf(bl[colbase + nt * 16], g1[nt], btv[nt]);
  };

  // Pipelined GEMM: entry contract af[0]/af[1] = kt0/kt1 of tile Tk (issued
  // by the caller BEFORE the epi block -> ~400cy cover), bb[0]/bb[1] = kt0/
  // kt1 of layer wl (tail-prefetched by the previous phase across the
  // barrier). Each buffer is refilled 2 mfma-clusters (~310cy) before use.
  // Tail stages prefetch wl_next's kt0/kt1 (Kt even -> parity lines up).
  auto run_gemm = [&](const _Float16* __restrict__ wl,
                      const _Float16* __restrict__ wl_next, int Kt, int Tk) {
#pragma unroll
    for (int s = 0; s < 8; ++s) {
      if (s < Kt) {
        __builtin_amdgcn_s_setprio(1);
        domfma(af[s & 1], bb[s & 1]);
        __builtin_amdgcn_s_setprio(0);
        if (s + 2 < Kt) {
          loadA(Tk, s + 2, af[s & 1]);
          loadB(wl, s + 2, bb[s & 1]);
        } else if (wl_next) {
          loadB(wl_next, s - (Kt - 2), bb[s & 1]);
        }
      }
    }
  };

  const _Float16* wp0 = wpack + (size_t)KT0 * KTU;
  const _Float16* wp1 = wpack + (size_t)KT1 * KTU;
  const _Float16* wp2 = wpack + (size_t)KT2 * KTU;
  const _Float16* wp3 = wpack + (size_t)KT3 * KTU;

  // phase 1: G(A,L0); tail prefetches (B,L0)'s kt0/kt1 (same wp0)
  loadB(wp0, 0, bb[0]);
  loadB(wp0, 1, bb[1]);
  loadA(0, 0, af[0]);
  loadA(0, 1, af[1]);
  zero();
  run_gemm(wp0, wp0, 6, 0);
  __syncthreads();

  // phase 2: E(A,L0) + G(B,L0); prefetch L1
  loadA(1, 0, af[0]); loadA(1, 1, af[1]);
  set_cb(b0); epi_all(0);
  zero();
  run_gemm(wp0, wp1, 6, 1);
  __syncthreads();

  // phase 3: E(B,L0) + G(A,L1)
  loadA(0, 0, af[0]); loadA(0, 1, af[1]);
  set_cb(b0); epi_all(1);
  zero();
  run_gemm(wp1, wp1, 8, 0);
  __syncthreads();

  // phase 4: E(A,L1) + G(B,L1); prefetch L2
  loadA(1, 0, af[0]); loadA(1, 1, af[1]);
  set_cb(b1); epi_all(0);
  zero();
  run_gemm(wp1, wp2, 8, 1);
  __syncthreads();

  // phase 5: E(B,L1) + G(A,L2)
  loadA(0, 0, af[0]); loadA(0, 1, af[1]);
  set_cb(b1); epi_all(1);
  zero();
  run_gemm(wp2, wp2, 8, 0);
  __syncthreads();

  // phase 6: E(A,L2) + G(B,L2); prefetch L3
  loadA(1, 0, af[0]); loadA(1, 1, af[1]);
  set_cb(b2); epi_all(0);
  zero();
  run_gemm(wp2, wp3, 8, 1);
  __syncthreads();

  // phase 7: E(B,L2) + G(A,L3)
  loadA(0, 0, af[0]); loadA(0, 1, af[1]);
  set_cb(b2); epi_all(1);
  zero();
  run_gemm(wp3, wp3, 8, 0);
  __syncthreads();

  // phase 8: E(A,L3) + G(B,L3); no next prefetch (Kout uses wob layout)
  loadA(1, 0, af[0]); loadA(1, 1, af[1]);
  set_cb(b3); epi_all(0);
  zero();
  run_gemm(wp3, nullptr, 8, 1);
  __syncthreads();

  // phase 9: E(B,L3) [all waves] + Kout(tile A) [waves 0..3] + store A
  {
    set_cb(b3);
    const _Float16* wob = wpack + OUT_OFF;
    f32x4 oacc = (f32x4){0.f, 0.f, 0.f, 0.f};
    const int rb = (wc & 3) * 16 + ((wc < 4) ? 0 : 64);  // wave's 16-row slice
#pragma unroll
    for (int s = 0; s < 8; ++s) {
      if (wc < 4) {
        const f16x8 bfr = *(const f16x8*)(wob + (size_t)(s * 64 + lane) * 8);
        const f16x8 afr = *(const f16x8*)(act + (rb + arow) * LDK + s * 32 + kq);
        oacc = __builtin_amdgcn_mfma_f32_16x16x32_f16(afr, bfr, oacc, 0, 0, 0);
      }
      epi_group(s, 1);
    }
    if (wc < 4) {
      const int col = lane & 15;
      if (col < 3) {
        const float bv = bo[col];
        const int rowb = rb + (lane >> 4) * 4;
#pragma unroll
        for (int r = 0; r < 4; ++r)
          out[((size_t)b * NPTS + n0 + rowb + r) * 3 + col] = tanh_fast(oacc[r] + bv);
      }
    }
    __syncthreads();

    // phase 10: Kout(tile B) [waves 4..7] + store B
    if (wc >= 4) {
      f32x4 oacc2 = (f32x4){0.f, 0.f, 0.f, 0.f};
#pragma unroll
      for (int kt = 0; kt < 8; ++kt) {
        const f16x8 bfr = *(const f16x8*)(wob + (size_t)(kt * 64 + lane) * 8);
        const f16x8 afr = *(const f16x8*)(act + (rb + arow) * LDK + kt * 32 + kq);
        oacc2 = __builtin_amdgcn_mfma_f32_16x16x32_f16(afr, bfr, oacc2, 0, 0, 0);
      }
      const int col = lane & 15;
      if (col < 3) {
        const float bv = bo[col];
        const int rowb = rb + (lane >> 4) * 4;
#pragma unroll
        for (int r = 0; r < 4; ++r)
          out[((size_t)b * NPTS + n0 + rowb + r) * 3 + col] = tanh_fast(oacc2[r] + bv);
      }
    }
  }
}

extern "C" void kernel_launch(void* const* d_in, const int* in_sizes, int n_in,
                              void* d_out, int out_size, void* d_ws, size_t ws_size,
                              hipStream_t stream) {
  const float* grid   = (const float*)d_in[0];
  const float* ctx    = (const float*)d_in[1];
  const float* coords = (const float*)d_in[2];
  const float* w0 = (const float*)d_in[3];
  const float* b0 = (const float*)d_in[4];
  const float* w1 = (const float*)d_in[5];
  const float* b1 = (const float*)d_in[6];
  const float* w2 = (const float*)d_in[7];
  const float* b2 = (const float*)d_in[8];
  const float* w3 = (const float*)d_in[9];
  const float* b3 = (const float*)d_in[10];
  const float* wf = (const float*)d_in[11];
  const float* bf = (const float*)d_in[12];
  const float* wo = (const float*)d_in[13];
  const float* bo = (const float*)d_in[14];
  float* out = (float*)d_out;

  float* filmbuf = (float*)d_ws;
  _Float16* wpack = (_Float16*)((char*)d_ws + 8192);

  hipLaunchKernelGGL(prep_kernel, dim3(126), dim3(256), 0, stream,
                     w0, w1, w2, w3, wo, ctx, wf, bf, wpack, filmbuf);
  hipLaunchKernelGGL(decoder_kernel, dim3(NB * (NPTS / MT)), dim3(TPB), 0, stream,
                     grid, coords, b0, b1, b2, b3, bo, filmbuf, wpack, out);
}

// Round 8
// 271.354 us; speedup vs baseline: 1.0558x; 1.0558x over previous
//
#include <hip/hip_runtime.h>
#include <hip/hip_fp16.h>
#include <math.h>

#define NB 4
#define GH 64
#define GW 64
#define DM 128
#define MW 256
#define NF 10
#define NPTS 65536
#define ENCD 42
#define MT 128         // points per block: two 64-pt half-tiles A (rows 0-63) and B (64-127)
#define TPB 512
#define LDK 264        // act row stride in f16

typedef _Float16 f16x8 __attribute__((ext_vector_type(8)));
typedef __fp16 h16x2 __attribute__((ext_vector_type(2)));
typedef __fp16 h16x4 __attribute__((ext_vector_type(4)));
typedef float f32x4 __attribute__((ext_vector_type(4)));

// d_ws: [0,8192) film fp32 (4x512); [8192,...) packed f16 weights.
// 16x16x32 B-frags: unit = (ktg*16 + nt)*64 + lane, 8 halves each.
#define KTU 8192
#define KT0 0
#define KT1 6
#define KT2 14
#define KT3 22
#define KT_TOTAL 30
#define NUNIT_MAIN (KT_TOTAL * 16 * 64)
#define NUNIT_OUT (8 * 64)
#define OUT_OFF ((size_t)NUNIT_MAIN * 8)

__device__ __forceinline__ float tanh_fast(float v) {
  const float e = __builtin_amdgcn_exp2f(2.8853900818f * v);
  return 1.0f - 2.0f * __builtin_amdgcn_rcpf(1.0f + e);
}

// Fused prep: blocks [0,122) pack weights; blocks [122,126) compute film.
__global__ void prep_kernel(const float* __restrict__ w0, const float* __restrict__ w1,
                            const float* __restrict__ w2, const float* __restrict__ w3,
                            const float* __restrict__ wo,
                            const float* __restrict__ ctx, const float* __restrict__ wf,
                            const float* __restrict__ bf,
                            _Float16* __restrict__ wp, float* __restrict__ filmout) {
  if (blockIdx.x >= 122) {
    const int b = blockIdx.x - 122;
#pragma unroll
    for (int h = 0; h < 2; ++h) {
      const int j = threadIdx.x + h * 256;
      float acc = bf[j];
      for (int k = 0; k < DM; ++k)
        acc = fmaf(ctx[b * DM + k], wf[k * 512 + j], acc);
      filmout[b * 512 + j] = acc;
    }
    return;
  }
  const int u = blockIdx.x * 256 + threadIdx.x;
  const int lane = u & 63;
  if (u < NUNIT_MAIN) {
    const int v = u >> 6;
    const int nt = v & 15;
    const int ktg = v >> 4;
    const float* w; int ktl, K;
    if (ktg < KT1)      { w = w0; ktl = ktg - KT0; K = 170; }
    else if (ktg < KT2) { w = w1; ktl = ktg - KT1; K = 256; }
    else if (ktg < KT3) { w = w2; ktl = ktg - KT2; K = 256; }
    else                { w = w3; ktl = ktg - KT3; K = 256; }
    const int n = nt * 16 + (lane & 15);
    const int kbase = ktl * 32 + (lane >> 4) * 8;
    _Float16* dst = wp + (size_t)u * 8;
#pragma unroll
    for (int j = 0; j < 8; ++j) {
      const int k = kbase + j;
      dst[j] = (_Float16)((k < K) ? w[k * MW + n] : 0.0f);
    }
  } else {
    const int kt = (u - NUNIT_MAIN) >> 6;
    const int col = lane & 15;
    const int kbase = kt * 32 + (lane >> 4) * 8;
    _Float16* dst = wp + (size_t)u * 8;
#pragma unroll
    for (int j = 0; j < 8; ++j)
      dst[j] = (_Float16)((col < 3) ? wo[(kbase + j) * 3 + col] : 0.0f);
  }
}

__global__ __launch_bounds__(TPB, 4) void decoder_kernel(
    const float* __restrict__ grid, const float* __restrict__ coords,
    const float* __restrict__ b0, const float* __restrict__ b1,
    const float* __restrict__ b2, const float* __restrict__ b3,
    const float* __restrict__ bo,
    const float* __restrict__ film, const _Float16* __restrict__ wpack,
    float* __restrict__ out) {
  __shared__ _Float16 act[MT * LDK];   // 67584 B; rows 0-63 = tile A, 64-127 = tile B
  __shared__ float4 cco4[MT];          // 2048 B
  __shared__ float g1s[MW];            // 1024 B: gamma+1 per col
  __shared__ float cbs[4 * MW];        // 4096 B: per-layer bias*g1+beta
  // total ~74.8 KB < 80 KB/block -> still 2 blocks/CU

  const int tid = threadIdx.x;
  const int lane = tid & 63;
  const int wc = tid >> 6;             // wave 0..7: owns cols wc*32..wc*32+31 (disjoint)
  const int b = blockIdx.x >> 9;
  const int n0 = (blockIdx.x & 511) * MT;

  // packed-GELU constants (hoisted)
  const __half2 gk1 = __float2half2_rn(-2.3022082f);
  const __half2 gk2 = __float2half2_rn(-0.10294324f);
  const __half2 one2 = __float2half2_rn(1.0f);

  // ---- per-point bilinear setup ----
  if (tid < MT) {
    const float x = coords[(size_t)(n0 + tid) * 2 + 0];
    const float y = coords[(size_t)(n0 + tid) * 2 + 1];
    const float cr = (x + 1.0f) * 0.5f * 63.0f;
    const float cc = (y + 1.0f) * 0.5f * 63.0f;
    const float r0f = floorf(cr), q0f = floorf(cc);
    const int r0 = min(max((int)r0f, 0), GH - 1);
    const int q0 = min(max((int)q0f, 0), GW - 1);
    float4 v;
    v.x = __int_as_float(r0);
    v.y = __int_as_float(q0);
    v.z = cr - r0f;
    v.w = cc - q0f;
    cco4[tid] = v;
  }

  // ---- FiLM tables: g1s[c] = gamma[c]+1; cbs[l][c] = bias_l[c]*g1 + beta[c].
  // Identical arithmetic to the old per-wave set_cb (bit-exact), but held in
  // LDS so the GEMM phase carries zero film registers; epi reads are 16-lane
  // broadcasts (conflict-free).
  if (tid < MW) {
    const float g = film[b * 512 + tid] + 1.0f;
    const float be = film[b * 512 + MW + tid];
    g1s[tid] = g;
    cbs[0 * MW + tid] = fmaf(b0[tid], g, be);
    cbs[1 * MW + tid] = fmaf(b1[tid], g, be);
    cbs[2 * MW + tid] = fmaf(b2[tid], g, be);
    cbs[3 * MW + tid] = fmaf(b3[tid], g, be);
  }

  // ---- positional encoding (hw sin/cos, revolutions) + zero-pad 170..191 ----
  {
    const int p = tid & (MT - 1);
    const int j = tid >> 7;
    const float x = coords[(size_t)(n0 + p) * 2 + 0];
    const float y = coords[(size_t)(n0 + p) * 2 + 1];
    _Float16* row = act + p * LDK;
    if (j == 0) { row[0] = (_Float16)x; row[1] = (_Float16)y; }
    if (j == 1) {
      for (int c = ENCD + DM; c < ENCD + DM + 22; ++c) row[c] = (_Float16)0.0f;
    }
    for (int i = j; i < NF; i += 4) {
      const float sc = 0.5f * (float)(1 << i);
      const float rx = x * sc, ry = y * sc;
      const float fx = rx - floorf(rx);
      const float fy = ry - floorf(ry);
      row[2 + 4 * i + 0] = (_Float16)__builtin_amdgcn_sinf(fx);
      row[2 + 4 * i + 1] = (_Float16)__builtin_amdgcn_sinf(fy);
      row[2 + 4 * i + 2] = (_Float16)__builtin_amdgcn_cosf(fx);
      row[2 + 4 * i + 3] = (_Float16)__builtin_amdgcn_cosf(fy);
    }
  }
  __syncthreads();

  // ---- bilinear sampling, 4 channels/iter ----
  {
    const float* gb = grid + (size_t)b * (GH * GW * DM);
#pragma unroll
    for (int it = 0; it < (MT * DM / 4) / TPB; ++it) {
      const int idx = it * TPB + tid;
      const int p = idx >> 5;
      const int c = (idx & 31) * 4;
      const float4 cc4 = cco4[p];
      const int r0 = __float_as_int(cc4.x);
      const int q0 = __float_as_int(cc4.y);
      const float frr = cc4.z, frc = cc4.w;
      const int r1 = min(r0 + 1, GH - 1), q1 = min(q0 + 1, GW - 1);
      const float4 v00 = *(const float4*)(gb + (size_t)(r0 * GW + q0) * DM + c);
      const float4 v01 = *(const float4*)(gb + (size_t)(r0 * GW + q1) * DM + c);
      const float4 v10 = *(const float4*)(gb + (size_t)(r1 * GW + q0) * DM + c);
      const float4 v11 = *(const float4*)(gb + (size_t)(r1 * GW + q1) * DM + c);
      float4 vt, vb, vv;
      vt.x = fmaf(v01.x - v00.x, frc, v00.x);
      vt.y = fmaf(v01.y - v00.y, frc, v00.y);
      vt.z = fmaf(v01.z - v00.z, frc, v00.z);
      vt.w = fmaf(v01.w - v00.w, frc, v00.w);
      vb.x = fmaf(v11.x - v10.x, frc, v10.x);
      vb.y = fmaf(v11.y - v10.y, frc, v10.y);
      vb.z = fmaf(v11.z - v10.z, frc, v10.z);
      vb.w = fmaf(v11.w - v10.w, frc, v10.w);
      vv.x = fmaf(vb.x - vt.x, frr, vt.x);
      vv.y = fmaf(vb.y - vt.y, frr, vt.y);
      vv.z = fmaf(vb.z - vt.z, frr, vt.z);
      vv.w = fmaf(vb.w - vt.w, frr, vt.w);
      const h16x2 lo = __builtin_amdgcn_cvt_pkrtz(vv.x, vv.y);
      const h16x2 hi = __builtin_amdgcn_cvt_pkrtz(vv.z, vv.w);
      *(h16x2*)(act + p * LDK + ENCD + c) = lo;
      *(h16x2*)(act + p * LDK + ENCD + c + 2) = hi;
    }
  }
  __syncthreads();

  const int arow = lane & 15;
  const int kq = (lane >> 4) * 8;

  f32x4 accA[4][2], accB[4][2];
  const f32x4 zc = (f32x4){0.f, 0.f, 0.f, 0.f};  // MFMA C for s==0: kills 32 accvgpr zero-writes/seg

  // fragment loaders
  auto loadB = [&](const _Float16* __restrict__ wl, int kt, f16x8 (&bfr)[2]) {
#pragma unroll
    for (int nt = 0; nt < 2; ++nt)
      bfr[nt] = *(const f16x8*)(wl + ((size_t)((kt * 16 + wc * 2 + nt) * 64 + lane)) * 8);
  };
  auto loadA = [&](int T, int kt, f16x8 (&afr)[4]) {
    const int kof = kt * 32 + kq;
#pragma unroll
    for (int mt = 0; mt < 4; ++mt)
      afr[mt] = *(const f16x8*)(act + (T * 64 + mt * 16 + arow) * LDK + kof);
  };
  // SWAPPED operand order: mfma(W, act, C). a- and b-operand fragment layouts
  // use the identical lane<->(m/n,k) mapping, so the same register bits work
  // in either slot — no repacking. D becomes [w-col][point]: each lane holds
  // 4 CONSECUTIVE weight-cols of one point -> epi collapses to 1 ds_write_b64.
  auto domfma = [&](f16x8 (&afr)[4], f16x8 (&bfr)[2], f32x4 (&acc)[4][2], int init) {
#pragma unroll
    for (int mt = 0; mt < 4; ++mt)
#pragma unroll
      for (int nt = 0; nt < 2; ++nt)
        acc[mt][nt] = __builtin_amdgcn_mfma_f32_16x16x32_f16(
            bfr[nt], afr[mt], init ? zc : acc[mt][nt], 0, 0, 0);
  };

  // packed-f16 GELU on a pair: g = h * rcp(1 + exp2(h * (gk1 + gk2*h^2)))
  auto gelu_pk = [&](h16x2 pk) -> h16x2 {
    __half2 hv = __builtin_bit_cast(__half2, pk);
    __half2 t = __hmul2(hv, hv);
    __half2 w = __hfma2(gk2, t, gk1);
    __half2 z = __hmul2(hv, w);
    __half2 e = h2exp2(z);
    __half2 s = __hadd2(e, one2);
    __half2 r = h2rcp(s);
    __half2 g = __hmul2(hv, r);
    return __builtin_bit_cast(h16x2, g);
  };

  // one epilogue group (of 8) for tile T, layer table cbl: g -> (mt,nt).
  // Swapped-D layout: point = T*64+mt*16+(lane&15); cols nb..nb+3.
  auto epi_group = [&](int gI, int T, const float* __restrict__ cbl,
                       f32x4 (&acc)[4][2]) {
    const int mt = gI >> 1, nt = gI & 1;
    const int nb = wc * 32 + nt * 16 + ((lane >> 4) << 2);
    const int pt = T * 64 + mt * 16 + (lane & 15);
    const float4 g4 = *(const float4*)(g1s + nb);      // 16-lane broadcast
    const float4 c4 = *(const float4*)(cbl + nb);      // 16-lane broadcast
    const float v0 = fmaf(acc[mt][nt][0], g4.x, c4.x);
    const float v1 = fmaf(acc[mt][nt][1], g4.y, c4.y);
    const float v2 = fmaf(acc[mt][nt][2], g4.z, c4.z);
    const float v3 = fmaf(acc[mt][nt][3], g4.w, c4.w);
    const h16x2 gA = gelu_pk(__builtin_amdgcn_cvt_pkrtz(v0, v1));
    const h16x2 gB = gelu_pk(__builtin_amdgcn_cvt_pkrtz(v2, v3));
    const h16x4 o = (h16x4){gA.x, gA.y, gB.x, gB.y};
    *(h16x4*)(act + pt * LDK + nb) = o;                // one ds_write_b64
  };

  // Stage order (best-known from R2): loadA(s) -> epi(s) -> mfma(s) -> loadB(s+2).
  auto run_seg = [&](const _Float16* __restrict__ wl, int Kt, int Tk,
                     f32x4 (&accK)[4][2], bool do_epi, const float* __restrict__ cbl,
                     int Te, f32x4 (&accE)[4][2]) {
    f16x8 bb[2][2];
    loadB(wl, 0, bb[0]);
    if (Kt > 1) loadB(wl, 1, bb[1]);
    f16x8 afr[4];
#pragma unroll
    for (int s = 0; s < 8; ++s) {
      if (s < Kt) loadA(Tk, s, afr);
      if (do_epi) epi_group(s, Te, cbl, accE);
      if (s < Kt) {
        __builtin_amdgcn_s_setprio(1);
        domfma(afr, bb[s & 1], accK, s == 0);
        __builtin_amdgcn_s_setprio(0);
        if (s + 2 < Kt) loadB(wl, s + 2, bb[s & 1]);
      }
    }
  };

  const _Float16* wp0 = wpack + (size_t)KT0 * KTU;
  const _Float16* wp1 = wpack + (size_t)KT1 * KTU;
  const _Float16* wp2 = wpack + (size_t)KT2 * KTU;
  const _Float16* wp3 = wpack + (size_t)KT3 * KTU;
  const float* cb0 = cbs + 0 * MW;
  const float* cb1 = cbs + 1 * MW;
  const float* cb2 = cbs + 2 * MW;
  const float* cb3 = cbs + 3 * MW;

  // seg0: K(A,0)
  run_seg(wp0, 6, 0, accA, false, cb0, 0, accB);
  __syncthreads();

  // seg1: E(A,0) + K(B,0)
  run_seg(wp0, 6, 1, accB, true, cb0, 0, accA);
  __syncthreads();

  // seg2: E(B,0) + K(A,1)
  run_seg(wp1, 8, 0, accA, true, cb0, 1, accB);
  __syncthreads();

  // seg3: E(A,1) + K(B,1)
  run_seg(wp1, 8, 1, accB, true, cb1, 0, accA);
  __syncthreads();

  // seg4: E(B,1) + K(A,2)
  run_seg(wp2, 8, 0, accA, true, cb1, 1, accB);
  __syncthreads();

  // seg5: E(A,2) + K(B,2)
  run_seg(wp2, 8, 1, accB, true, cb2, 0, accA);
  __syncthreads();

  // seg6: E(B,2) + K(A,3)
  run_seg(wp3, 8, 0, accA, true, cb2, 1, accB);
  __syncthreads();

  // seg7: E(A,3) + K(B,3)
  run_seg(wp3, 8, 1, accB, true, cb3, 0, accA);
  __syncthreads();

  // seg8: E(B,3) [all waves] + Kout(tile A) [waves 0..3] + store A
  // Kout keeps the ORIGINAL operand order (act in a-slot) so its D layout and
  // the out-store mapping are unchanged.
  {
    const _Float16* wob = wpack + OUT_OFF;
    f32x4 oacc = (f32x4){0.f, 0.f, 0.f, 0.f};
    const int rb = (wc & 3) * 16 + ((wc < 4) ? 0 : 64);  // wave's 16-row slice
#pragma unroll
    for (int s = 0; s < 8; ++s) {
      if (wc < 4) {
        const f16x8 bfr = *(const f16x8*)(wob + (size_t)(s * 64 + lane) * 8);
        const f16x8 afr = *(const f16x8*)(act + (rb + arow) * LDK + s * 32 + kq);
        oacc = __builtin_amdgcn_mfma_f32_16x16x32_f16(afr, bfr, oacc, 0, 0, 0);
      }
      epi_group(s, 1, cb3, accB);
    }
    if (wc < 4) {
      const int col = lane & 15;
      if (col < 3) {
        const float bv = bo[col];
        const int rowb = rb + (lane >> 4) * 4;
#pragma unroll
        for (int r = 0; r < 4; ++r)
          out[((size_t)b * NPTS + n0 + rowb + r) * 3 + col] = tanh_fast(oacc[r] + bv);
      }
    }
    __syncthreads();

    // seg9: Kout(tile B) [waves 4..7] + store B
    if (wc >= 4) {
      f32x4 oacc2 = (f32x4){0.f, 0.f, 0.f, 0.f};
#pragma unroll
      for (int kt = 0; kt < 8; ++kt) {
        const f16x8 bfr = *(const f16x8*)(wob + (size_t)(kt * 64 + lane) * 8);
        const f16x8 afr = *(const f16x8*)(act + (rb + arow) * LDK + kt * 32 + kq);
        oacc2 = __builtin_amdgcn_mfma_f32_16x16x32_f16(afr, bfr, oacc2, 0, 0, 0);
      }
      const int col = lane & 15;
      if (col < 3) {
        const float bv = bo[col];
        const int rowb = rb + (lane >> 4) * 4;
#pragma unroll
        for (int r = 0; r < 4; ++r)
          out[((size_t)b * NPTS + n0 + rowb + r) * 3 + col] = tanh_fast(oacc2[r] + bv);
      }
    }
  }
}

extern "C" void kernel_launch(void* const* d_in, const int* in_sizes, int n_in,
                              void* d_out, int out_size, void* d_ws, size_t ws_size,
                              hipStream_t stream) {
  const float* grid   = (const float*)d_in[0];
  const float* ctx    = (const float*)d_in[1];
  const float* coords = (const float*)d_in[2];
  const float* w0 = (const float*)d_in[3];
  const float* b0 = (const float*)d_in[4];
  const float* w1 = (const float*)d_in[5];
  const float* b1 = (const float*)d_in[6];
  const float* w2 = (const float*)d_in[7];
  const float* b2 = (const float*)d_in[8];
  const float* w3 = (const float*)d_in[9];
  const float* b3 = (const float*)d_in[10];
  const float* wf = (const float*)d_in[11];
  const float* bf = (const float*)d_in[12];
  const float* wo = (const float*)d_in[13];
  const float* bo = (const float*)d_in[14];
  float* out = (float*)d_out;

  float* filmbuf = (float*)d_ws;
  _Float16* wpack = (_Float16*)((char*)d_ws + 8192);

  hipLaunchKernelGGL(prep_kernel, dim3(126), dim3(256), 0, stream,
                     w0, w1, w2, w3, wo, ctx, wf, bf, wpack, filmbuf);
  hipLaunchKernelGGL(decoder_kernel, dim3(NB * (NPTS / MT)), dim3(TPB), 0, stream,
                     grid, coords, b0, b1, b2, b3, bo, filmbuf, wpack, out);
}